// Round 10
// baseline (770.151 us; speedup 1.0000x reference)
//
#include <hip/hip_runtime.h>
#include <stdint.h>
#include <math.h>

#define K_CODES 4096
#define DIM 128
#define N_FLAT 32768      // 32 * 32 * 32
#define HW 1024           // 32*32 spatial per batch

// output offsets (floats): quantized_st, loss, perplexity, encodings, indices
#define OFF_Q    0
#define OFF_LOSS 4194304
#define OFF_PERP 4194305
#define OFF_ENC  4194306
#define OFF_IDX  138412034

// workspace offsets (bytes)
#define WS_PACKED 0                        // 32768 * 8
#define WS_COUNTS 262144                   // 4096 * 4
#define WS_WSQ    278528                   // 4096 * 4
#define WS_XSQ    294912                   // 32768 * 4
#define WS_PART   425984                   // 1024 * 4
#define WS_XHL    430080                   // 32768 rows * 256 f16 = 16 MB
#define WS_WHL    (WS_XHL + 16777216)      // 4096 rows * 256 f16 = 2 MB

typedef _Float16 f16x8 __attribute__((ext_vector_type(8)));
typedef float    f32x4 __attribute__((ext_vector_type(4)));

// f16 plane rows: [row][0:128]=h, [row][128:256]=l (512 B). Exact pow2
// scales x*32, w*1024 -> acc = 2^15*dot, unscale by 2^-14 is exact.

// ---------------- K1: w_sq + counts zero. grid 1024 x 256 (4 waves = 4 k) --
__global__ __launch_bounds__(256) void wsq_kernel(const float* __restrict__ w,
                                                  float* __restrict__ wsq,
                                                  float* __restrict__ counts) {
    int wave = threadIdx.x >> 6, lane = threadIdx.x & 63;
    int k = blockIdx.x * 4 + wave;
    float a = w[k * DIM + lane];
    float b = w[k * DIM + lane + 64];
    float s = a * a + b * b;
    #pragma unroll
    for (int o = 32; o > 0; o >>= 1) s += __shfl_down(s, o, 64);
    if (lane == 0) { wsq[k] = s; counts[k] = 0.f; }
}

// ---------------- K2: w -> f16 h/l planes ----------------------------------
__global__ __launch_bounds__(256) void wplanes_kernel(const float* __restrict__ w,
                                                      _Float16* __restrict__ whl) {
    int T = blockIdx.x * 256 + threadIdx.x;
    int k = T >> 2, seg = T & 3;
    const float* wp = w + (size_t)k * DIM + seg * 32;
    _Float16* row = whl + (size_t)k * 256;
    #pragma unroll
    for (int q = 0; q < 4; ++q) {
        float4 a = *(const float4*)(wp + q * 8);
        float4 b = *(const float4*)(wp + q * 8 + 4);
        float vv[8] = {a.x, a.y, a.z, a.w, b.x, b.y, b.z, b.w};
        f16x8 hv, lv;
        #pragma unroll
        for (int j = 0; j < 8; ++j) {
            float v = 1024.0f * vv[j];
            _Float16 h = (_Float16)v;
            _Float16 l = (_Float16)(v - (float)h);
            hv[j] = h; lv[j] = l;
        }
        *(f16x8*)(row + seg * 32 + q * 8) = hv;
        *(f16x8*)(row + 128 + seg * 32 + q * 8) = lv;
    }
}

// ---------------- K3: x -> planes + x_sq + packed init (fused) -------------
__global__ __launch_bounds__(256) void xprep_kernel(const float* __restrict__ x,
                                                    _Float16* __restrict__ xhl,
                                                    float* __restrict__ xsq,
                                                    unsigned long long* __restrict__ packed) {
    __shared__ float xt[128 * 65];            // [c][n], pad 65
    const int t = threadIdx.x;
    const int n0 = blockIdx.x * 64;
    const int b = n0 >> 10, hw0 = n0 & 1023;
    const float* xg = x + (size_t)b * (DIM * HW) + hw0;
    #pragma unroll
    for (int i = 0; i < 16; ++i) {
        int idx = i * 256 + t;                // 4096 float2
        int c = idx >> 5, n2 = (idx & 31) << 1;
        float2 v = *(const float2*)(xg + c * HW + n2);
        xt[c * 65 + n2] = v.x;
        xt[c * 65 + n2 + 1] = v.y;
    }
    __syncthreads();
    if (t < 64) {
        packed[n0 + t] = ~0ull;
        float s = 0.f;                        // strict c order, fp32 (== ref path)
        #pragma unroll
        for (int c = 0; c < DIM; ++c) {
            float v = xt[c * 65 + t];
            s = fmaf(v, v, s);
        }
        xsq[n0 + t] = s;
    }
    const int n = t >> 2, seg = t & 3;
    _Float16* row = xhl + (size_t)(n0 + n) * 256;
    #pragma unroll
    for (int q = 0; q < 4; ++q) {
        f16x8 hv, lv;
        #pragma unroll
        for (int j = 0; j < 8; ++j) {
            float v = 32.0f * xt[(seg * 32 + q * 8 + j) * 65 + n];
            _Float16 h = (_Float16)v;
            _Float16 l = (_Float16)(v - (float)h);
            hv[j] = h; lv[j] = l;
        }
        *(f16x8*)(row + seg * 32 + q * 8) = hv;
        *(f16x8*)(row + 128 + seg * 32 + q * 8) = lv;
    }
}

// ---------------- K4 (R10): R8 + counted-vmcnt step barriers (T4) ----------
// grid (256 n-tiles, 8 k-supertiles), block 256 = 4 waves 2x2, 128n x 512k
// per block, 16 (ks,c0) steps, LDS dbuf, global_load_lds w=16 staging with
// T21 both-sides XOR swizzle (R8/R9, verified absmax 0.0).
// R10 change: per-step __syncthreads (vmcnt(0) drain incl. enc stores)
// replaced for s>=1 by `s_waitcnt vmcnt(4)` + raw s_barrier. Per-step VMEM
// issue order pinned: [wk loads (c0==0), 8 gloads, sched_barrier(0),
// 4 enc float4 stores] -> the 4 NEWEST ops at the wait are always this
// step's stores; vmcnt(4) retires (in-order, m135) all gloads + older
// stores, leaving the stores a full step of latency cover. s==0 keeps a
// full __syncthreads (prologue ops outstanding); final __syncthreads
// drains everything before the packed atomics. Numerics untouched.
__global__ __launch_bounds__(256) void dist_argmin(
    const _Float16* __restrict__ xhl, const _Float16* __restrict__ whl,
    const float* __restrict__ wsq, const float* __restrict__ xsq,
    unsigned long long* __restrict__ packed, float* __restrict__ enc)
{
    __shared__ __align__(16) char xlds[2][16384];   // [row][128B] linear
    __shared__ __align__(16) char wlds[2][16384];
    __shared__ float xsq_s[128];
    __shared__ unsigned long long red[128];

    const int tid  = threadIdx.x;
    const int lane = tid & 63, wave = tid >> 6;
    const int lq   = lane & 15, quad = lane >> 4;
    const int wn0  = (wave >> 1) * 64, wk0 = (wave & 1) * 64;
    const int n0   = blockIdx.x * 128;
    const int kbase = blockIdx.y * 512;

    // ---- staging constants (gload_lds dest = buf + wave*4096 + i*1024 +
    // lane*16 -> row = wave*32 + i*8 + (lane>>3), pc = (lane&7)*16) --------
    const int r0 = wave * 32 + (lane >> 3);               // row at i=0
    const int lc = (((lane & 7) ^ (lane >> 3)) << 4);     // logical byte col
    const int lcAdj = lc + ((lc >> 6) * 192);             // l-plane: +192
    const char* xB = (const char*)xhl;
    const char* wB = (const char*)whl;
    const size_t xrow0 = (size_t)(n0 + r0) * 512;

    // ---- fragment read offsets (logical [h32|l32] row, XOR swizzle) ------
    const int swz  = (lq & 7) << 4;
    const int hoff = (quad << 4) ^ swz;
    const int loff = (64 | (quad << 4)) ^ swz;

    float* ebase = enc + (size_t)n0 * K_CODES + kbase;
    if (tid < 128) {
        float2 z2; z2.x = 0.f; z2.y = 0.f;
        *(float2*)(ebase + (size_t)tid * K_CODES) = z2;   // head cols 0..1
        xsq_s[tid] = xsq[n0 + tid];
        red[tid] = ~0ull;
    }

#define GLOAD16(gp, lp) __builtin_amdgcn_global_load_lds(                      \
        (const __attribute__((address_space(1))) void*)(gp),                   \
        (__attribute__((address_space(3))) void*)(lp), 16, 0, 0)

    // ---- prologue: stage step 0 (ks=0, c0=0) into buffer 0 ---------------
    {
        const size_t wrow0 = (size_t)(kbase + r0) * 512;
        #pragma unroll
        for (int i = 0; i < 4; ++i) {
            GLOAD16(xB + xrow0 + (size_t)i * 4096 + lcAdj,
                    xlds[0] + wave * 4096 + i * 1024);
            GLOAD16(wB + wrow0 + (size_t)i * 4096 + lcAdj,
                    wlds[0] + wave * 4096 + i * 1024);
        }
    }

    f32x4 acc[4][4];
    float wk[4];

    for (int s = 0; s < 16; ++s) {
        const int p  = s & 1;
        const int ks = s >> 2, c0 = s & 3;
        const int k0 = kbase + ks * 128;

        if (s == 0) {
            __syncthreads();          // full drain: prologue gloads + misc
        } else {
            // counted wait: the 4 newest VMEM ops are prev step's enc
            // stores; everything older (gloads, wk loads, older stores)
            // retires. Then raw barrier; sched fence stops hoisting.
            asm volatile("s_waitcnt vmcnt(4)" ::: "memory");
            __builtin_amdgcn_s_barrier();
            __builtin_amdgcn_sched_barrier(0);
        }

        if (c0 == 0) {
            #pragma unroll
            for (int ki = 0; ki < 4; ++ki)
                wk[ki] = wsq[k0 + wk0 + ki * 16 + lq];   // L1-hot, fp32-exact
            #pragma unroll
            for (int i = 0; i < 4; ++i)
                #pragma unroll
                for (int j = 0; j < 4; ++j)
                    acc[i][j] = (f32x4){0.f, 0.f, 0.f, 0.f};
        }

        // frag reads from buf[p]
        f16x8 ah[4], al[4], bh[4], bl[4];
        const char* xb = xlds[p];
        const char* wb = wlds[p];
        #pragma unroll
        for (int i = 0; i < 4; ++i) {
            int xr = (wn0 + 16 * i + lq) * 128;
            ah[i] = *(const f16x8*)(xb + xr + hoff);
            al[i] = *(const f16x8*)(xb + xr + loff);
            int wr = (wk0 + 16 * i + lq) * 128;
            bh[i] = *(const f16x8*)(wb + wr + hoff);
            bl[i] = *(const f16x8*)(wb + wr + loff);
        }

        // stage step s+1 into buf[p^1] (async; retired by next step's wait)
        if (s < 15) {
            const int s1 = s + 1, ks1 = s1 >> 2, c01 = s1 & 3;
            const int offX = c01 * 64 + lcAdj;
            const size_t wrow0 = (size_t)(kbase + ks1 * 128 + r0) * 512;
            char* xd = xlds[p ^ 1] + wave * 4096;
            char* wd = wlds[p ^ 1] + wave * 4096;
            #pragma unroll
            for (int i = 0; i < 4; ++i) {
                GLOAD16(xB + xrow0 + (size_t)i * 4096 + offX, xd + i * 1024);
                GLOAD16(wB + wrow0 + (size_t)i * 4096 + offX, wd + i * 1024);
            }
        }
        // pin order: all gloads issued before the enc stores below, so the
        // stores are guaranteed the newest vmcnt events at the next wait.
        __builtin_amdgcn_sched_barrier(0);

        // enc zero-fill batch s (R3 mapping, coalesced; 4 float4 stores)
        {
            float4 z4; z4.x = z4.y = z4.z = z4.w = 0.f;
            #pragma unroll
            for (int j = 0; j < 4; ++j) {
                int idx = s * 1024 + j * 256 + tid;
                int r = idx >> 7, c4 = idx & 127;
                *(float4*)(ebase + (size_t)r * K_CODES + 2 + c4 * 4) = z4;
            }
        }

        #pragma unroll
        for (int ki = 0; ki < 4; ++ki)
            #pragma unroll
            for (int ni = 0; ni < 4; ++ni) {
                acc[ni][ki] = __builtin_amdgcn_mfma_f32_16x16x32_f16(
                    ah[ni], bh[ki], acc[ni][ki], 0, 0, 0);
                acc[ni][ki] = __builtin_amdgcn_mfma_f32_16x16x32_f16(
                    ah[ni], bl[ki], acc[ni][ki], 0, 0, 0);
                acc[ni][ki] = __builtin_amdgcn_mfma_f32_16x16x32_f16(
                    al[ni], bh[ki], acc[ni][ki], 0, 0, 0);
            }

        if (c0 == 3) {   // per-ks epilogue: distances + argmin -> LDS red[]
            #pragma unroll
            for (int ni = 0; ni < 4; ++ni) {
                #pragma unroll
                for (int rg = 0; rg < 4; ++rg) {
                    int rowl = wn0 + ni * 16 + quad * 4 + rg;
                    float xr = xsq_s[rowl];
                    float best = 3.4e38f; int bk = 0;
                    #pragma unroll
                    for (int ki = 0; ki < 4; ++ki) {
                        int kl = wk0 + ki * 16 + lq;
                        float t = xr - acc[ni][ki][rg] * 6.103515625e-05f; // 2^-14
                        t += wk[ki];
                        t += 1e-8f;
                        if (t < best) { best = t; bk = k0 + kl; }
                    }
                    unsigned u = __float_as_uint(best);
                    u = (u & 0x80000000u) ? ~u : (u | 0x80000000u);
                    unsigned long long pck =
                        ((unsigned long long)u << 32) | (unsigned)bk;
                    #pragma unroll
                    for (int m = 1; m < 16; m <<= 1) {
                        unsigned long long o = __shfl_xor(pck, m, 64);
                        if (o < pck) pck = o;
                    }
                    if (lq == 0) atomicMin(&red[rowl], pck);
                }
            }
        }
    }
#undef GLOAD16

    __syncthreads();   // full drain: enc stores + red atomics complete
    if (tid < 128) atomicMin(&packed[n0 + tid], red[tid]);
}

// ---------------- K5: combine -> indices, one-hot 1.0, counts ---------------
__global__ __launch_bounds__(256) void combine(
    const unsigned long long* __restrict__ packed,
    float* __restrict__ idxf, float* __restrict__ enc,
    float* __restrict__ counts)
{
    int n = blockIdx.x * 256 + threadIdx.x;
    unsigned k = (unsigned)(packed[n] & 0xFFFFFFFFu);
    idxf[n] = (float)k;
    enc[(size_t)n * K_CODES + k] = 1.0f;
    atomicAdd(&counts[k], 1.0f);
}

// ---------------- K6: gather -> quantized_st (NCHW) + per-block loss partial
__global__ __launch_bounds__(256) void quantize_loss(
    const float* __restrict__ x, const float* __restrict__ w,
    const float* __restrict__ idxf, float* __restrict__ outq,
    float* __restrict__ part)
{
    const int base4 = (blockIdx.x * 256 + threadIdx.x) * 4;
    float s = 0.f;
    #pragma unroll
    for (int i = 0; i < 4; ++i) {
        int e  = base4 + i * 1048576;      // NCHW element index (x4 aligned)
        int hw = e & 1023;
        int c  = (e >> 10) & 127;
        int b  = e >> 17;
        int n  = (b << 10) | hw;           // multiple of 4
        float4 xv = *(const float4*)(x + e);
        float4 kf = *(const float4*)(idxf + n);
        float q0 = w[(int)kf.x * DIM + c];
        float q1 = w[(int)kf.y * DIM + c];
        float q2 = w[(int)kf.z * DIM + c];
        float q3 = w[(int)kf.w * DIM + c];
        float4 df; df.x = q0 - xv.x; df.y = q1 - xv.y;
                   df.z = q2 - xv.z; df.w = q3 - xv.w;
        float4 o;  o.x = xv.x + df.x; o.y = xv.y + df.y;
                   o.z = xv.z + df.z; o.w = xv.w + df.w;
        *(float4*)(outq + e) = o;
        s = fmaf(df.x, df.x, s);
        s = fmaf(df.y, df.y, s);
        s = fmaf(df.z, df.z, s);
        s = fmaf(df.w, df.w, s);
    }
    #pragma unroll
    for (int o = 32; o > 0; o >>= 1) s += __shfl_down(s, o, 64);
    __shared__ float ls[4];
    if ((threadIdx.x & 63) == 0) ls[threadIdx.x >> 6] = s;
    __syncthreads();
    if (threadIdx.x == 0) part[blockIdx.x] = ls[0] + ls[1] + ls[2] + ls[3];
}

// ---------------- K7: loss (from partials) + perplexity ---------------------
__global__ __launch_bounds__(256) void finalize(
    const float* __restrict__ counts, const float* __restrict__ part,
    float* __restrict__ out)
{
    __shared__ float sh[512];
    float h = 0.f;
    for (int k = threadIdx.x; k < K_CODES; k += 256) {
        float p = counts[k] * (1.0f / N_FLAT);
        h += p * logf(p + 1e-10f);
    }
    float s = 0.f;
    for (int i = threadIdx.x; i < 1024; i += 256) s += part[i];
    sh[threadIdx.x] = h;
    sh[256 + threadIdx.x] = s;
    __syncthreads();
    #pragma unroll
    for (int st = 128; st > 0; st >>= 1) {
        if (threadIdx.x < st) {
            sh[threadIdx.x] += sh[threadIdx.x + st];
            sh[256 + threadIdx.x] += sh[256 + threadIdx.x + st];
        }
        __syncthreads();
    }
    if (threadIdx.x == 0) {
        float perp = expf(-sh[0]);
        float loss = 1.25f * (sh[256] / 4194304.0f);
        if (isnan(loss) || isinf(loss)) loss = 0.1f;
        out[OFF_LOSS] = loss;
        out[OFF_PERP] = perp;
    }
}

extern "C" void kernel_launch(void* const* d_in, const int* in_sizes, int n_in,
                              void* d_out, int out_size, void* d_ws, size_t ws_size,
                              hipStream_t stream) {
    const float* x = (const float*)d_in[0];   // [32,128,32,32] fp32 NCHW
    const float* w = (const float*)d_in[1];   // [4096,128] fp32
    float* out = (float*)d_out;
    char* ws = (char*)d_ws;

    unsigned long long* packed = (unsigned long long*)(ws + WS_PACKED);
    float* counts = (float*)(ws + WS_COUNTS);
    float* wsq    = (float*)(ws + WS_WSQ);
    float* xsq    = (float*)(ws + WS_XSQ);
    float* part   = (float*)(ws + WS_PART);
    _Float16* xhl = (_Float16*)(ws + WS_XHL);
    _Float16* whl = (_Float16*)(ws + WS_WHL);

    wsq_kernel<<<K_CODES / 4, 256, 0, stream>>>(w, wsq, counts);
    wplanes_kernel<<<K_CODES * 4 / 256, 256, 0, stream>>>(w, whl);
    xprep_kernel<<<N_FLAT / 64, 256, 0, stream>>>(x, xhl, xsq, packed);

    dim3 g2(256, 8);
    dist_argmin<<<g2, 256, 0, stream>>>(xhl, whl, wsq, xsq, packed,
                                        out + OFF_ENC);

    combine<<<N_FLAT / 256, 256, 0, stream>>>(packed, out + OFF_IDX,
                                              out + OFF_ENC, counts);

    quantize_loss<<<1024, 256, 0, stream>>>(x, w, out + OFF_IDX,
                                            out + OFF_Q, part);

    finalize<<<1, 256, 0, stream>>>(counts, part, out);
}

// Round 11
// 766.140 us; speedup vs baseline: 1.0052x; 1.0052x over previous
//
#include <hip/hip_runtime.h>
#include <stdint.h>
#include <math.h>

#define K_CODES 4096
#define DIM 128
#define N_FLAT 32768      // 32 * 32 * 32
#define HW 1024           // 32*32 spatial per batch

// output offsets (floats): quantized_st, loss, perplexity, encodings, indices
#define OFF_Q    0
#define OFF_LOSS 4194304
#define OFF_PERP 4194305
#define OFF_ENC  4194306
#define OFF_IDX  138412034

// workspace offsets (bytes)
#define WS_PACKED 0                        // 32768 * 8
#define WS_COUNTS 262144                   // 4096 * 4
#define WS_WSQ    278528                   // 4096 * 4
#define WS_XSQ    294912                   // 32768 * 4
#define WS_PART   425984                   // 1024 * 4
#define WS_XHL    430080                   // 32768 rows * 256 f16 = 16 MB
#define WS_WHL    (WS_XHL + 16777216)      // 4096 rows * 256 f16 = 2 MB

typedef _Float16 f16x8 __attribute__((ext_vector_type(8)));
typedef float    f32x4 __attribute__((ext_vector_type(4)));

// f16 plane rows: [row][0:128]=h, [row][128:256]=l (512 B). Exact pow2
// scales x*32, w*1024 -> acc = 2^15*dot, unscale by 2^-14 is exact.

// ---------------- K1: w_sq + counts zero. grid 1024 x 256 (4 waves = 4 k) --
__global__ __launch_bounds__(256) void wsq_kernel(const float* __restrict__ w,
                                                  float* __restrict__ wsq,
                                                  float* __restrict__ counts) {
    int wave = threadIdx.x >> 6, lane = threadIdx.x & 63;
    int k = blockIdx.x * 4 + wave;
    float a = w[k * DIM + lane];
    float b = w[k * DIM + lane + 64];
    float s = a * a + b * b;
    #pragma unroll
    for (int o = 32; o > 0; o >>= 1) s += __shfl_down(s, o, 64);
    if (lane == 0) { wsq[k] = s; counts[k] = 0.f; }
}

// ---------------- K2: w -> f16 h/l planes ----------------------------------
__global__ __launch_bounds__(256) void wplanes_kernel(const float* __restrict__ w,
                                                      _Float16* __restrict__ whl) {
    int T = blockIdx.x * 256 + threadIdx.x;
    int k = T >> 2, seg = T & 3;
    const float* wp = w + (size_t)k * DIM + seg * 32;
    _Float16* row = whl + (size_t)k * 256;
    #pragma unroll
    for (int q = 0; q < 4; ++q) {
        float4 a = *(const float4*)(wp + q * 8);
        float4 b = *(const float4*)(wp + q * 8 + 4);
        float vv[8] = {a.x, a.y, a.z, a.w, b.x, b.y, b.z, b.w};
        f16x8 hv, lv;
        #pragma unroll
        for (int j = 0; j < 8; ++j) {
            float v = 1024.0f * vv[j];
            _Float16 h = (_Float16)v;
            _Float16 l = (_Float16)(v - (float)h);
            hv[j] = h; lv[j] = l;
        }
        *(f16x8*)(row + seg * 32 + q * 8) = hv;
        *(f16x8*)(row + 128 + seg * 32 + q * 8) = lv;
    }
}

// ---------------- K3: x -> planes + x_sq + packed init (fused) -------------
__global__ __launch_bounds__(256) void xprep_kernel(const float* __restrict__ x,
                                                    _Float16* __restrict__ xhl,
                                                    float* __restrict__ xsq,
                                                    unsigned long long* __restrict__ packed) {
    __shared__ float xt[128 * 65];            // [c][n], pad 65
    const int t = threadIdx.x;
    const int n0 = blockIdx.x * 64;
    const int b = n0 >> 10, hw0 = n0 & 1023;
    const float* xg = x + (size_t)b * (DIM * HW) + hw0;
    #pragma unroll
    for (int i = 0; i < 16; ++i) {
        int idx = i * 256 + t;                // 4096 float2
        int c = idx >> 5, n2 = (idx & 31) << 1;
        float2 v = *(const float2*)(xg + c * HW + n2);
        xt[c * 65 + n2] = v.x;
        xt[c * 65 + n2 + 1] = v.y;
    }
    __syncthreads();
    if (t < 64) {
        packed[n0 + t] = ~0ull;
        float s = 0.f;                        // strict c order, fp32 (== ref path)
        #pragma unroll
        for (int c = 0; c < DIM; ++c) {
            float v = xt[c * 65 + t];
            s = fmaf(v, v, s);
        }
        xsq[n0 + t] = s;
    }
    const int n = t >> 2, seg = t & 3;
    _Float16* row = xhl + (size_t)(n0 + n) * 256;
    #pragma unroll
    for (int q = 0; q < 4; ++q) {
        f16x8 hv, lv;
        #pragma unroll
        for (int j = 0; j < 8; ++j) {
            float v = 32.0f * xt[(seg * 32 + q * 8 + j) * 65 + n];
            _Float16 h = (_Float16)v;
            _Float16 l = (_Float16)(v - (float)h);
            hv[j] = h; lv[j] = l;
        }
        *(f16x8*)(row + seg * 32 + q * 8) = hv;
        *(f16x8*)(row + 128 + seg * 32 + q * 8) = lv;
    }
}

// ---------------- K4 (R11): R9 structure, 8 waves (4 waves/SIMD) -----------
// grid (256 n-tiles, 8 k-supertiles), block 512 = 8 waves 2x4, 128n x 512k
// per block, 16 (ks,c0) steps, LDS dbuf 64KB, global_load_lds w=16 with
// T21 both-sides XOR swizzle (verified absmax 0.0 in R9/R10).
// R11 change (R10 post-mortem: counted-vmcnt null => drain wasn't the cost;
// MfmaUtil ~11% at 2 waves/SIMD is an occupancy/issue limit): 512 threads,
// wave tile 64n x 32k (was 64x64). Per-wave: acc[4][2]=32 VGPR, X frags 32,
// W frags 16, 4 gloads + 2 enc stores per step -> est ~120 VGPR live. If
// allocator lands <=128: 16 waves/CU = 4 waves/SIMD (2x latency coverage).
// NO forced launch-bounds min-waves (R2/R5 spill lesson). Plain
// __syncthreads per step (counted vmcnt proven null in R10).
// Numerics bit-identical: same staged values/swizzle (wave*16 = 0 mod 8 so
// r&7 = lane>>3 unchanged), same MFMA order (hH,hL,lH; c0 ascending), same
// t formula / packed-u64 argmin tie-break.
__global__ __launch_bounds__(512) void dist_argmin(
    const _Float16* __restrict__ xhl, const _Float16* __restrict__ whl,
    const float* __restrict__ wsq, const float* __restrict__ xsq,
    unsigned long long* __restrict__ packed, float* __restrict__ enc)
{
    __shared__ __align__(16) char xlds[2][16384];   // [128 rows][128 B] linear
    __shared__ __align__(16) char wlds[2][16384];
    __shared__ float xsq_s[128];
    __shared__ unsigned long long red[128];

    const int tid  = threadIdx.x;
    const int lane = tid & 63, wave = tid >> 6;     // wave 0..7
    const int lq   = lane & 15, quad = lane >> 4;
    const int wn0  = (wave >> 2) * 64;              // 0 | 64
    const int wk0q = (wave & 3) * 32;               // 0,32,64,96 in k-chunk
    const int n0   = blockIdx.x * 128;
    const int kbase = blockIdx.y * 512;

    // ---- staging constants: dest = buf + wave*2048 + i*1024 + lane*16 ->
    // row = wave*16 + i*8 + (lane>>3), pc = (lane&7)*16. wave*16 = 0 mod 8
    // so row&7 = lane>>3 (same swizzle math as the verified 4-wave form). --
    const int r0 = wave * 16 + (lane >> 3);               // row at i=0
    const int lc = (((lane & 7) ^ (lane >> 3)) << 4);     // logical byte col
    const int lcAdj = lc + ((lc >> 6) * 192);             // l-plane: +192
    const char* xB = (const char*)xhl;
    const char* wB = (const char*)whl;
    const size_t xrow0 = (size_t)(n0 + r0) * 512;

    // ---- fragment read offsets (logical [h32|l32] row, XOR swizzle) ------
    const int swz  = (lq & 7) << 4;
    const int hoff = (quad << 4) ^ swz;
    const int loff = (64 | (quad << 4)) ^ swz;

    float* ebase = enc + (size_t)n0 * K_CODES + kbase;
    if (tid < 128) {
        float2 z2; z2.x = 0.f; z2.y = 0.f;
        *(float2*)(ebase + (size_t)tid * K_CODES) = z2;   // head cols 0..1
        xsq_s[tid] = xsq[n0 + tid];
        red[tid] = ~0ull;
    }

#define GLOAD16(gp, lp) __builtin_amdgcn_global_load_lds(                      \
        (const __attribute__((address_space(1))) void*)(gp),                   \
        (__attribute__((address_space(3))) void*)(lp), 16, 0, 0)

    // ---- prologue: stage step 0 (ks=0, c0=0) into buffer 0 ---------------
    {
        const size_t wrow0 = (size_t)(kbase + r0) * 512;
        #pragma unroll
        for (int i = 0; i < 2; ++i) {
            GLOAD16(xB + xrow0 + (size_t)i * 4096 + lcAdj,
                    xlds[0] + wave * 2048 + i * 1024);
            GLOAD16(wB + wrow0 + (size_t)i * 4096 + lcAdj,
                    wlds[0] + wave * 2048 + i * 1024);
        }
    }

    f32x4 acc[4][2];
    float wk[2];

    for (int s = 0; s < 16; ++s) {
        const int p  = s & 1;
        const int ks = s >> 2, c0 = s & 3;
        const int k0 = kbase + ks * 128;
        if (c0 == 0) {
            wk[0] = wsq[k0 + wk0q + lq];
            wk[1] = wsq[k0 + wk0q + 16 + lq];
            #pragma unroll
            for (int i = 0; i < 4; ++i)
                #pragma unroll
                for (int j = 0; j < 2; ++j)
                    acc[i][j] = (f32x4){0.f, 0.f, 0.f, 0.f};
        }
        // barrier (with compiler vmcnt/lgkmcnt drain): step-s staging landed;
        // all waves' step s-1 LDS reads retired -> safe to re-stage buf[p^1].
        __syncthreads();

        // frag reads from buf[p]
        f16x8 ah[4], al[4], bh[2], bl[2];
        const char* xb = xlds[p];
        const char* wb = wlds[p];
        #pragma unroll
        for (int i = 0; i < 4; ++i) {
            int xr = (wn0 + 16 * i + lq) * 128;
            ah[i] = *(const f16x8*)(xb + xr + hoff);
            al[i] = *(const f16x8*)(xb + xr + loff);
        }
        #pragma unroll
        for (int ki = 0; ki < 2; ++ki) {
            int wr = (wk0q + 16 * ki + lq) * 128;
            bh[ki] = *(const f16x8*)(wb + wr + hoff);
            bl[ki] = *(const f16x8*)(wb + wr + loff);
        }

        // stage step s+1 into buf[p^1] (async; completes by next barrier)
        if (s < 15) {
            const int s1 = s + 1, ks1 = s1 >> 2, c01 = s1 & 3;
            const int offX = c01 * 64 + lcAdj;
            const size_t wrow0 = (size_t)(kbase + ks1 * 128 + r0) * 512;
            char* xd = xlds[p ^ 1] + wave * 2048;
            char* wd = wlds[p ^ 1] + wave * 2048;
            #pragma unroll
            for (int i = 0; i < 2; ++i) {
                GLOAD16(xB + xrow0 + (size_t)i * 4096 + offX, xd + i * 1024);
                GLOAD16(wB + wrow0 + (size_t)i * 4096 + offX, wd + i * 1024);
            }
        }

        // enc zero-fill batch s (coalesced; 2 float4 stores per thread)
        {
            float4 z4; z4.x = z4.y = z4.z = z4.w = 0.f;
            #pragma unroll
            for (int j = 0; j < 2; ++j) {
                int idx = s * 1024 + j * 512 + tid;
                int r = idx >> 7, c4 = idx & 127;
                *(float4*)(ebase + (size_t)r * K_CODES + 2 + c4 * 4) = z4;
            }
        }

        #pragma unroll
        for (int ki = 0; ki < 2; ++ki)
            #pragma unroll
            for (int ni = 0; ni < 4; ++ni) {
                acc[ni][ki] = __builtin_amdgcn_mfma_f32_16x16x32_f16(
                    ah[ni], bh[ki], acc[ni][ki], 0, 0, 0);
                acc[ni][ki] = __builtin_amdgcn_mfma_f32_16x16x32_f16(
                    ah[ni], bl[ki], acc[ni][ki], 0, 0, 0);
                acc[ni][ki] = __builtin_amdgcn_mfma_f32_16x16x32_f16(
                    al[ni], bh[ki], acc[ni][ki], 0, 0, 0);
            }

        if (c0 == 3) {   // per-ks epilogue: distances + argmin -> LDS red[]
            #pragma unroll
            for (int ni = 0; ni < 4; ++ni) {
                #pragma unroll
                for (int rg = 0; rg < 4; ++rg) {
                    int rowl = wn0 + ni * 16 + quad * 4 + rg;
                    float xr = xsq_s[rowl];
                    float best = 3.4e38f; int bk = 0;
                    #pragma unroll
                    for (int ki = 0; ki < 2; ++ki) {
                        int kl = wk0q + ki * 16 + lq;
                        float t = xr - acc[ni][ki][rg] * 6.103515625e-05f; // 2^-14
                        t += wk[ki];
                        t += 1e-8f;
                        if (t < best) { best = t; bk = k0 + kl; }
                    }
                    unsigned u = __float_as_uint(best);
                    u = (u & 0x80000000u) ? ~u : (u | 0x80000000u);
                    unsigned long long pck =
                        ((unsigned long long)u << 32) | (unsigned)bk;
                    #pragma unroll
                    for (int m = 1; m < 16; m <<= 1) {
                        unsigned long long o = __shfl_xor(pck, m, 64);
                        if (o < pck) pck = o;
                    }
                    if (lq == 0) atomicMin(&red[rowl], pck);
                }
            }
        }
    }
#undef GLOAD16

    __syncthreads();
    if (tid < 128) atomicMin(&packed[n0 + tid], red[tid]);
}

// ---------------- K5: combine -> indices, one-hot 1.0, counts ---------------
__global__ __launch_bounds__(256) void combine(
    const unsigned long long* __restrict__ packed,
    float* __restrict__ idxf, float* __restrict__ enc,
    float* __restrict__ counts)
{
    int n = blockIdx.x * 256 + threadIdx.x;
    unsigned k = (unsigned)(packed[n] & 0xFFFFFFFFu);
    idxf[n] = (float)k;
    enc[(size_t)n * K_CODES + k] = 1.0f;
    atomicAdd(&counts[k], 1.0f);
}

// ---------------- K6: gather -> quantized_st (NCHW) + per-block loss partial
__global__ __launch_bounds__(256) void quantize_loss(
    const float* __restrict__ x, const float* __restrict__ w,
    const float* __restrict__ idxf, float* __restrict__ outq,
    float* __restrict__ part)
{
    const int base4 = (blockIdx.x * 256 + threadIdx.x) * 4;
    float s = 0.f;
    #pragma unroll
    for (int i = 0; i < 4; ++i) {
        int e  = base4 + i * 1048576;      // NCHW element index (x4 aligned)
        int hw = e & 1023;
        int c  = (e >> 10) & 127;
        int b  = e >> 17;
        int n  = (b << 10) | hw;           // multiple of 4
        float4 xv = *(const float4*)(x + e);
        float4 kf = *(const float4*)(idxf + n);
        float q0 = w[(int)kf.x * DIM + c];
        float q1 = w[(int)kf.y * DIM + c];
        float q2 = w[(int)kf.z * DIM + c];
        float q3 = w[(int)kf.w * DIM + c];
        float4 df; df.x = q0 - xv.x; df.y = q1 - xv.y;
                   df.z = q2 - xv.z; df.w = q3 - xv.w;
        float4 o;  o.x = xv.x + df.x; o.y = xv.y + df.y;
                   o.z = xv.z + df.z; o.w = xv.w + df.w;
        *(float4*)(outq + e) = o;
        s = fmaf(df.x, df.x, s);
        s = fmaf(df.y, df.y, s);
        s = fmaf(df.z, df.z, s);
        s = fmaf(df.w, df.w, s);
    }
    #pragma unroll
    for (int o = 32; o > 0; o >>= 1) s += __shfl_down(s, o, 64);
    __shared__ float ls[4];
    if ((threadIdx.x & 63) == 0) ls[threadIdx.x >> 6] = s;
    __syncthreads();
    if (threadIdx.x == 0) part[blockIdx.x] = ls[0] + ls[1] + ls[2] + ls[3];
}

// ---------------- K7: loss (from partials) + perplexity ---------------------
__global__ __launch_bounds__(256) void finalize(
    const float* __restrict__ counts, const float* __restrict__ part,
    float* __restrict__ out)
{
    __shared__ float sh[512];
    float h = 0.f;
    for (int k = threadIdx.x; k < K_CODES; k += 256) {
        float p = counts[k] * (1.0f / N_FLAT);
        h += p * logf(p + 1e-10f);
    }
    float s = 0.f;
    for (int i = threadIdx.x; i < 1024; i += 256) s += part[i];
    sh[threadIdx.x] = h;
    sh[256 + threadIdx.x] = s;
    __syncthreads();
    #pragma unroll
    for (int st = 128; st > 0; st >>= 1) {
        if (threadIdx.x < st) {
            sh[threadIdx.x] += sh[threadIdx.x + st];
            sh[256 + threadIdx.x] += sh[256 + threadIdx.x + st];
        }
        __syncthreads();
    }
    if (threadIdx.x == 0) {
        float perp = expf(-sh[0]);
        float loss = 1.25f * (sh[256] / 4194304.0f);
        if (isnan(loss) || isinf(loss)) loss = 0.1f;
        out[OFF_LOSS] = loss;
        out[OFF_PERP] = perp;
    }
}

extern "C" void kernel_launch(void* const* d_in, const int* in_sizes, int n_in,
                              void* d_out, int out_size, void* d_ws, size_t ws_size,
                              hipStream_t stream) {
    const float* x = (const float*)d_in[0];   // [32,128,32,32] fp32 NCHW
    const float* w = (const float*)d_in[1];   // [4096,128] fp32
    float* out = (float*)d_out;
    char* ws = (char*)d_ws;

    unsigned long long* packed = (unsigned long long*)(ws + WS_PACKED);
    float* counts = (float*)(ws + WS_COUNTS);
    float* wsq    = (float*)(ws + WS_WSQ);
    float* xsq    = (float*)(ws + WS_XSQ);
    float* part   = (float*)(ws + WS_PART);
    _Float16* xhl = (_Float16*)(ws + WS_XHL);
    _Float16* whl = (_Float16*)(ws + WS_WHL);

    wsq_kernel<<<K_CODES / 4, 256, 0, stream>>>(w, wsq, counts);
    wplanes_kernel<<<K_CODES * 4 / 256, 256, 0, stream>>>(w, whl);
    xprep_kernel<<<N_FLAT / 64, 256, 0, stream>>>(x, xhl, xsq, packed);

    dim3 g2(256, 8);
    dist_argmin<<<g2, 512, 0, stream>>>(xhl, whl, wsq, xsq, packed,
                                        out + OFF_ENC);

    combine<<<N_FLAT / 256, 256, 0, stream>>>(packed, out + OFF_IDX,
                                              out + OFF_ENC, counts);

    quantize_loss<<<1024, 256, 0, stream>>>(x, w, out + OFF_IDX,
                                            out + OFF_Q, part);

    finalize<<<1, 256, 0, stream>>>(counts, part, out);
}

// Round 12
// 758.758 us; speedup vs baseline: 1.0150x; 1.0097x over previous
//
#include <hip/hip_runtime.h>
#include <stdint.h>
#include <math.h>

#define K_CODES 4096
#define DIM 128
#define N_FLAT 32768      // 32 * 32 * 32
#define HW 1024           // 32*32 spatial per batch

// output offsets (floats): quantized_st, loss, perplexity, encodings, indices
#define OFF_Q    0
#define OFF_LOSS 4194304
#define OFF_PERP 4194305
#define OFF_ENC  4194306
#define OFF_IDX  138412034

// workspace offsets (bytes)
#define WS_PACKED 0                        // 32768 * 8
#define WS_COUNTS 262144                   // 4096 * 4
#define WS_WSQ    278528                   // 4096 * 4
#define WS_XSQ    294912                   // 32768 * 4
#define WS_PART   425984                   // 1024 * 4
#define WS_XHL    430080                   // 32768 rows * 256 f16 = 16 MB
#define WS_WHL    (WS_XHL + 16777216)      // 4096 rows * 256 f16 = 2 MB

typedef _Float16 f16x8 __attribute__((ext_vector_type(8)));
typedef float    f32x4 __attribute__((ext_vector_type(4)));

// f16 plane rows: [row][0:128]=h, [row][128:256]=l (512 B). Exact pow2
// scales x*32, w*1024 -> acc = 2^15*dot, unscale by 2^-14 is exact.

// ---------------- K1: w_sq + counts zero. grid 1024 x 256 (4 waves = 4 k) --
// NOTE: summation order (per-lane a*a+b*b then 64-lane shuffle tree) is
// part of the verified numerics -- do not restructure.
__global__ __launch_bounds__(256) void wsq_kernel(const float* __restrict__ w,
                                                  float* __restrict__ wsq,
                                                  float* __restrict__ counts) {
    int wave = threadIdx.x >> 6, lane = threadIdx.x & 63;
    int k = blockIdx.x * 4 + wave;
    float a = w[k * DIM + lane];
    float b = w[k * DIM + lane + 64];
    float s = a * a + b * b;
    #pragma unroll
    for (int o = 32; o > 0; o >>= 1) s += __shfl_down(s, o, 64);
    if (lane == 0) { wsq[k] = s; counts[k] = 0.f; }
}

// ---------------- K2: w -> f16 h/l planes ----------------------------------
__global__ __launch_bounds__(256) void wplanes_kernel(const float* __restrict__ w,
                                                      _Float16* __restrict__ whl) {
    int T = blockIdx.x * 256 + threadIdx.x;
    int k = T >> 2, seg = T & 3;
    const float* wp = w + (size_t)k * DIM + seg * 32;
    _Float16* row = whl + (size_t)k * 256;
    #pragma unroll
    for (int q = 0; q < 4; ++q) {
        float4 a = *(const float4*)(wp + q * 8);
        float4 b = *(const float4*)(wp + q * 8 + 4);
        float vv[8] = {a.x, a.y, a.z, a.w, b.x, b.y, b.z, b.w};
        f16x8 hv, lv;
        #pragma unroll
        for (int j = 0; j < 8; ++j) {
            float v = 1024.0f * vv[j];
            _Float16 h = (_Float16)v;
            _Float16 l = (_Float16)(v - (float)h);
            hv[j] = h; lv[j] = l;
        }
        *(f16x8*)(row + seg * 32 + q * 8) = hv;
        *(f16x8*)(row + 128 + seg * 32 + q * 8) = lv;
    }
}

// ---------------- K3: x -> planes + x_sq + packed init (fused) -------------
__global__ __launch_bounds__(256) void xprep_kernel(const float* __restrict__ x,
                                                    _Float16* __restrict__ xhl,
                                                    float* __restrict__ xsq,
                                                    unsigned long long* __restrict__ packed) {
    __shared__ float xt[128 * 65];            // [c][n], pad 65
    const int t = threadIdx.x;
    const int n0 = blockIdx.x * 64;
    const int b = n0 >> 10, hw0 = n0 & 1023;
    const float* xg = x + (size_t)b * (DIM * HW) + hw0;
    #pragma unroll
    for (int i = 0; i < 16; ++i) {
        int idx = i * 256 + t;                // 4096 float2
        int c = idx >> 5, n2 = (idx & 31) << 1;
        float2 v = *(const float2*)(xg + c * HW + n2);
        xt[c * 65 + n2] = v.x;
        xt[c * 65 + n2 + 1] = v.y;
    }
    __syncthreads();
    if (t < 64) {
        packed[n0 + t] = ~0ull;
        float s = 0.f;                        // strict c order, fp32 (== ref path)
        #pragma unroll
        for (int c = 0; c < DIM; ++c) {
            float v = xt[c * 65 + t];
            s = fmaf(v, v, s);
        }
        xsq[n0 + t] = s;
    }
    const int n = t >> 2, seg = t & 3;
    _Float16* row = xhl + (size_t)(n0 + n) * 256;
    #pragma unroll
    for (int q = 0; q < 4; ++q) {
        f16x8 hv, lv;
        #pragma unroll
        for (int j = 0; j < 8; ++j) {
            float v = 32.0f * xt[(seg * 32 + q * 8 + j) * 65 + n];
            _Float16 h = (_Float16)v;
            _Float16 l = (_Float16)(v - (float)h);
            hv[j] = h; lv[j] = l;
        }
        *(f16x8*)(row + seg * 32 + q * 8) = hv;
        *(f16x8*)(row + 128 + seg * 32 + q * 8) = lv;
    }
}

// ---------------- K4 (R12): 8 waves, VGPR-trimmed, nksup=4, XCD-grouped ----
// 1D grid 1024 blocks x 512 thr (8 waves 2n x 4k). Block: 128n x 1024k via
// 32 (ks,c0) steps (8 ks sub-tiles). LDS dbuf 64KB, global_load_lds w=16,
// T21 both-sides XOR swizzle (verified absmax 0.0 R9-R11).
// R12 changes (R11 post-mortem: live set ~128+ VGPR -> allocator >128 ->
// only 2 waves/SIMD; the "8-wave" block never raised occupancy):
//  (a) X fragments scoped per-ni inside the MFMA nest: live X frags 64->16
//      VGPR; est total ~100-115 -> 4 waves/SIMD, 2 blocks/CU. Bit-exact:
//      each acc[ni][ki] is an independent accumulator and still gets its
//      hH,hL,lH sequence in the same c0 order (loop-nest order across
//      different accumulators doesn't alter any accumulator's sequence).
//  (b) nksup 8->4 (kbase=y*1024): X re-stage traffic halves (128->64MB),
//      packed-atomic contention halves.
//  (c) XCD-grouping block swizzle: the 4 ksup-blocks sharing one X tile
//      get ids congruent mod 8 -> same XCD -> X re-reads L2-local.
//      Bijective: id=(t%8)+8*((t>>3)*4+y); perf-only mapping.
__global__ __launch_bounds__(512) void dist_argmin(
    const _Float16* __restrict__ xhl, const _Float16* __restrict__ whl,
    const float* __restrict__ wsq, const float* __restrict__ xsq,
    unsigned long long* __restrict__ packed, float* __restrict__ enc)
{
    __shared__ __align__(16) char xlds[2][16384];   // [128 rows][128 B] linear
    __shared__ __align__(16) char wlds[2][16384];
    __shared__ float xsq_s[128];
    __shared__ unsigned long long red[128];

    const int tid  = threadIdx.x;
    const int lane = tid & 63, wave = tid >> 6;     // wave 0..7
    const int lq   = lane & 15, quad = lane >> 4;
    const int wn0  = (wave >> 2) * 64;              // 0 | 64
    const int wk0q = (wave & 3) * 32;               // 0,32,64,96 in k-chunk

    // ---- XCD-grouped decode: t = n-tile (0..255), y = ksup (0..3) --------
    const int id  = blockIdx.x;
    const int xcd = id & 7, q = id >> 3;
    const int y   = q & 3;
    const int t   = (q >> 2) * 8 + xcd;
    const int n0    = t * 128;
    const int kbase = y * 1024;                     // k-row base

    // ---- staging constants: dest = buf + wave*2048 + i*1024 + lane*16 ->
    // row = wave*16 + i*8 + (lane>>3), pc = (lane&7)*16; wave*16 = 0 mod 8
    // so row&7 = lane>>3 (same verified swizzle math). ---------------------
    const int r0 = wave * 16 + (lane >> 3);               // row at i=0
    const int lc = (((lane & 7) ^ (lane >> 3)) << 4);     // logical byte col
    const int lcAdj = lc + ((lc >> 6) * 192);             // l-plane: +192
    const char* xB = (const char*)xhl;
    const char* wB = (const char*)whl;
    const size_t xrow0 = (size_t)(n0 + r0) * 512;

    // ---- fragment read offsets (logical [h32|l32] row, XOR swizzle) ------
    const int swz  = (lq & 7) << 4;
    const int hoff = (quad << 4) ^ swz;
    const int loff = (64 | (quad << 4)) ^ swz;

    float* ebase = enc + (size_t)n0 * K_CODES + kbase;
    if (tid < 128) {
        float2 z2; z2.x = 0.f; z2.y = 0.f;
        *(float2*)(ebase + (size_t)tid * K_CODES) = z2;   // head cols 0..1
        xsq_s[tid] = xsq[n0 + tid];
        red[tid] = ~0ull;
    }

#define GLOAD16(gp, lp) __builtin_amdgcn_global_load_lds(                      \
        (const __attribute__((address_space(1))) void*)(gp),                   \
        (__attribute__((address_space(3))) void*)(lp), 16, 0, 0)

    // ---- prologue: stage step 0 (ks=0, c0=0) into buffer 0 ---------------
    {
        const size_t wrow0 = (size_t)(kbase + r0) * 512;
        #pragma unroll
        for (int i = 0; i < 2; ++i) {
            GLOAD16(xB + xrow0 + (size_t)i * 4096 + lcAdj,
                    xlds[0] + wave * 2048 + i * 1024);
            GLOAD16(wB + wrow0 + (size_t)i * 4096 + lcAdj,
                    wlds[0] + wave * 2048 + i * 1024);
        }
    }

    f32x4 acc[4][2];
    float wk[2];

    for (int s = 0; s < 32; ++s) {
        const int p  = s & 1;
        const int ks = s >> 2, c0 = s & 3;
        const int k0 = kbase + ks * 128;
        if (c0 == 0) {
            wk[0] = wsq[k0 + wk0q + lq];
            wk[1] = wsq[k0 + wk0q + 16 + lq];
            #pragma unroll
            for (int i = 0; i < 4; ++i)
                #pragma unroll
                for (int j = 0; j < 2; ++j)
                    acc[i][j] = (f32x4){0.f, 0.f, 0.f, 0.f};
        }
        // barrier (with compiler vmcnt/lgkmcnt drain): step-s staging landed;
        // all waves' step s-1 LDS reads retired -> safe to re-stage buf[p^1].
        __syncthreads();

        const char* xb = xlds[p];
        const char* wb = wlds[p];

        // W frags (small, shared across ni): 32 VGPR live
        f16x8 bh[2], bl[2];
        #pragma unroll
        for (int ki = 0; ki < 2; ++ki) {
            int wr = (wk0q + 16 * ki + lq) * 128;
            bh[ki] = *(const f16x8*)(wb + wr + hoff);
            bl[ki] = *(const f16x8*)(wb + wr + loff);
        }

        // stage step s+1 into buf[p^1] (async; completes by next barrier)
        if (s < 31) {
            const int s1 = s + 1, ks1 = s1 >> 2, c01 = s1 & 3;
            const int offX = c01 * 64 + lcAdj;
            const size_t wrow0 = (size_t)(kbase + ks1 * 128 + r0) * 512;
            char* xd = xlds[p ^ 1] + wave * 2048;
            char* wd = wlds[p ^ 1] + wave * 2048;
            #pragma unroll
            for (int i = 0; i < 2; ++i) {
                GLOAD16(xB + xrow0 + (size_t)i * 4096 + offX, xd + i * 1024);
                GLOAD16(wB + wrow0 + (size_t)i * 4096 + offX, wd + i * 1024);
            }
        }

        // enc zero-fill batch s (coalesced; 2 float4 stores per thread).
        // idx 0..32767 covers 128 rows x 256 float4-slots (+2 shift; c4=255
        // spills 2 floats into next region = zero-over-zero / idxf head,
        // proven-benign pattern).
        {
            float4 z4; z4.x = z4.y = z4.z = z4.w = 0.f;
            #pragma unroll
            for (int j = 0; j < 2; ++j) {
                int idx = s * 1024 + j * 512 + tid;
                int r = idx >> 8, c4 = idx & 255;
                *(float4*)(ebase + (size_t)r * K_CODES + 2 + c4 * 4) = z4;
            }
        }

        // MFMA nest, X frags scoped per-ni (16 VGPR live instead of 64)
        #pragma unroll
        for (int ni = 0; ni < 4; ++ni) {
            int xr = (wn0 + 16 * ni + lq) * 128;
            f16x8 ah = *(const f16x8*)(xb + xr + hoff);
            f16x8 al = *(const f16x8*)(xb + xr + loff);
            #pragma unroll
            for (int ki = 0; ki < 2; ++ki) {
                acc[ni][ki] = __builtin_amdgcn_mfma_f32_16x16x32_f16(
                    ah, bh[ki], acc[ni][ki], 0, 0, 0);
                acc[ni][ki] = __builtin_amdgcn_mfma_f32_16x16x32_f16(
                    ah, bl[ki], acc[ni][ki], 0, 0, 0);
                acc[ni][ki] = __builtin_amdgcn_mfma_f32_16x16x32_f16(
                    al, bh[ki], acc[ni][ki], 0, 0, 0);
            }
        }

        if (c0 == 3) {   // per-ks epilogue: distances + argmin -> LDS red[]
            #pragma unroll
            for (int ni = 0; ni < 4; ++ni) {
                #pragma unroll
                for (int rg = 0; rg < 4; ++rg) {
                    int rowl = wn0 + ni * 16 + quad * 4 + rg;
                    float xr = xsq_s[rowl];
                    float best = 3.4e38f; int bk = 0;
                    #pragma unroll
                    for (int ki = 0; ki < 2; ++ki) {
                        int kl = wk0q + ki * 16 + lq;
                        float tt = xr - acc[ni][ki][rg] * 6.103515625e-05f; // 2^-14
                        tt += wk[ki];
                        tt += 1e-8f;
                        if (tt < best) { best = tt; bk = k0 + kl; }
                    }
                    unsigned u = __float_as_uint(best);
                    u = (u & 0x80000000u) ? ~u : (u | 0x80000000u);
                    unsigned long long pck =
                        ((unsigned long long)u << 32) | (unsigned)bk;
                    #pragma unroll
                    for (int m = 1; m < 16; m <<= 1) {
                        unsigned long long o = __shfl_xor(pck, m, 64);
                        if (o < pck) pck = o;
                    }
                    if (lq == 0) atomicMin(&red[rowl], pck);
                }
            }
        }
    }
#undef GLOAD16

    __syncthreads();
    if (tid < 128) atomicMin(&packed[n0 + tid], red[tid]);
}

// ---------------- K5: combine -> indices, one-hot 1.0, counts ---------------
__global__ __launch_bounds__(256) void combine(
    const unsigned long long* __restrict__ packed,
    float* __restrict__ idxf, float* __restrict__ enc,
    float* __restrict__ counts)
{
    int n = blockIdx.x * 256 + threadIdx.x;
    unsigned k = (unsigned)(packed[n] & 0xFFFFFFFFu);
    idxf[n] = (float)k;
    enc[(size_t)n * K_CODES + k] = 1.0f;
    atomicAdd(&counts[k], 1.0f);
}

// ---------------- K6: gather -> quantized_st (NCHW) + per-block loss partial
__global__ __launch_bounds__(256) void quantize_loss(
    const float* __restrict__ x, const float* __restrict__ w,
    const float* __restrict__ idxf, float* __restrict__ outq,
    float* __restrict__ part)
{
    const int base4 = (blockIdx.x * 256 + threadIdx.x) * 4;
    float s = 0.f;
    #pragma unroll
    for (int i = 0; i < 4; ++i) {
        int e  = base4 + i * 1048576;      // NCHW element index (x4 aligned)
        int hw = e & 1023;
        int c  = (e >> 10) & 127;
        int b  = e >> 17;
        int n  = (b << 10) | hw;           // multiple of 4
        float4 xv = *(const float4*)(x + e);
        float4 kf = *(const float4*)(idxf + n);
        float q0 = w[(int)kf.x * DIM + c];
        float q1 = w[(int)kf.y * DIM + c];
        float q2 = w[(int)kf.z * DIM + c];
        float q3 = w[(int)kf.w * DIM + c];
        float4 df; df.x = q0 - xv.x; df.y = q1 - xv.y;
                   df.z = q2 - xv.z; df.w = q3 - xv.w;
        float4 o;  o.x = xv.x + df.x; o.y = xv.y + df.y;
                   o.z = xv.z + df.z; o.w = xv.w + df.w;
        *(float4*)(outq + e) = o;
        s = fmaf(df.x, df.x, s);
        s = fmaf(df.y, df.y, s);
        s = fmaf(df.z, df.z, s);
        s = fmaf(df.w, df.w, s);
    }
    #pragma unroll
    for (int o = 32; o > 0; o >>= 1) s += __shfl_down(s, o, 64);
    __shared__ float ls[4];
    if ((threadIdx.x & 63) == 0) ls[threadIdx.x >> 6] = s;
    __syncthreads();
    if (threadIdx.x == 0) part[blockIdx.x] = ls[0] + ls[1] + ls[2] + ls[3];
}

// ---------------- K7: loss (from partials) + perplexity ---------------------
__global__ __launch_bounds__(256) void finalize(
    const float* __restrict__ counts, const float* __restrict__ part,
    float* __restrict__ out)
{
    __shared__ float sh[512];
    float h = 0.f;
    for (int k = threadIdx.x; k < K_CODES; k += 256) {
        float p = counts[k] * (1.0f / N_FLAT);
        h += p * logf(p + 1e-10f);
    }
    float s = 0.f;
    for (int i = threadIdx.x; i < 1024; i += 256) s += part[i];
    sh[threadIdx.x] = h;
    sh[256 + threadIdx.x] = s;
    __syncthreads();
    #pragma unroll
    for (int st = 128; st > 0; st >>= 1) {
        if (threadIdx.x < st) {
            sh[threadIdx.x] += sh[threadIdx.x + st];
            sh[256 + threadIdx.x] += sh[256 + threadIdx.x + st];
        }
        __syncthreads();
    }
    if (threadIdx.x == 0) {
        float perp = expf(-sh[0]);
        float loss = 1.25f * (sh[256] / 4194304.0f);
        if (isnan(loss) || isinf(loss)) loss = 0.1f;
        out[OFF_LOSS] = loss;
        out[OFF_PERP] = perp;
    }
}

extern "C" void kernel_launch(void* const* d_in, const int* in_sizes, int n_in,
                              void* d_out, int out_size, void* d_ws, size_t ws_size,
                              hipStream_t stream) {
    const float* x = (const float*)d_in[0];   // [32,128,32,32] fp32 NCHW
    const float* w = (const float*)d_in[1];   // [4096,128] fp32
    float* out = (float*)d_out;
    char* ws = (char*)d_ws;

    unsigned long long* packed = (unsigned long long*)(ws + WS_PACKED);
    float* counts = (float*)(ws + WS_COUNTS);
    float* wsq    = (float*)(ws + WS_WSQ);
    float* xsq    = (float*)(ws + WS_XSQ);
    float* part   = (float*)(ws + WS_PART);
    _Float16* xhl = (_Float16*)(ws + WS_XHL);
    _Float16* whl = (_Float16*)(ws + WS_WHL);

    wsq_kernel<<<K_CODES / 4, 256, 0, stream>>>(w, wsq, counts);
    wplanes_kernel<<<K_CODES * 4 / 256, 256, 0, stream>>>(w, whl);
    xprep_kernel<<<N_FLAT / 64, 256, 0, stream>>>(x, xhl, xsq, packed);

    dist_argmin<<<1024, 512, 0, stream>>>(xhl, whl, wsq, xsq, packed,
                                          out + OFF_ENC);

    combine<<<N_FLAT / 256, 256, 0, stream>>>(packed, out + OFF_IDX,
                                              out + OFF_ENC, counts);

    quantize_loss<<<1024, 256, 0, stream>>>(x, w, out + OFF_IDX,
                                            out + OFF_Q, part);

    finalize<<<1, 256, 0, stream>>>(counts, part, out);
}

// Round 14
// 712.455 us; speedup vs baseline: 1.0810x; 1.0650x over previous
//
#include <hip/hip_runtime.h>
#include <stdint.h>
#include <math.h>

#define K_CODES 4096
#define DIM 128
#define N_FLAT 32768      // 32 * 32 * 32
#define HW 1024           // 32*32 spatial per batch

// output offsets (floats): quantized_st, loss, perplexity, encodings, indices
#define OFF_Q    0
#define OFF_LOSS 4194304
#define OFF_PERP 4194305
#define OFF_ENC  4194306
#define OFF_IDX  138412034

// workspace offsets (bytes)
#define WS_PACKED 0                        // 32768 * 8
#define WS_COUNTS 262144                   // 4096 * 4
#define WS_WSQ    278528                   // 4096 * 4
#define WS_XSQ    294912                   // 32768 * 4
#define WS_PART   425984                   // 1024 * 4
#define WS_XHL    430080                   // 32768 rows * 256 f16 = 16 MB
#define WS_WHL    (WS_XHL + 16777216)      // 4096 rows * 256 f16 = 2 MB

typedef _Float16 f16x8 __attribute__((ext_vector_type(8)));
typedef float    f32x4 __attribute__((ext_vector_type(4)));

// f16 plane rows: [row][0:128]=h, [row][128:256]=l (512 B). Exact pow2
// scales x*32, w*1024 -> acc = 2^15*dot, unscale by 2^-14 is exact.

// ---------------- K1: w_sq + counts zero. grid 1024 x 256 (4 waves = 4 k) --
__global__ __launch_bounds__(256) void wsq_kernel(const float* __restrict__ w,
                                                  float* __restrict__ wsq,
                                                  float* __restrict__ counts) {
    int wave = threadIdx.x >> 6, lane = threadIdx.x & 63;
    int k = blockIdx.x * 4 + wave;
    float a = w[k * DIM + lane];
    float b = w[k * DIM + lane + 64];
    float s = a * a + b * b;
    #pragma unroll
    for (int o = 32; o > 0; o >>= 1) s += __shfl_down(s, o, 64);
    if (lane == 0) { wsq[k] = s; counts[k] = 0.f; }
}

// ---------------- K2: w -> f16 h/l planes ----------------------------------
__global__ __launch_bounds__(256) void wplanes_kernel(const float* __restrict__ w,
                                                      _Float16* __restrict__ whl) {
    int T = blockIdx.x * 256 + threadIdx.x;
    int k = T >> 2, seg = T & 3;
    const float* wp = w + (size_t)k * DIM + seg * 32;
    _Float16* row = whl + (size_t)k * 256;
    #pragma unroll
    for (int q = 0; q < 4; ++q) {
        float4 a = *(const float4*)(wp + q * 8);
        float4 b = *(const float4*)(wp + q * 8 + 4);
        float vv[8] = {a.x, a.y, a.z, a.w, b.x, b.y, b.z, b.w};
        f16x8 hv, lv;
        #pragma unroll
        for (int j = 0; j < 8; ++j) {
            float v = 1024.0f * vv[j];
            _Float16 h = (_Float16)v;
            _Float16 l = (_Float16)(v - (float)h);
            hv[j] = h; lv[j] = l;
        }
        *(f16x8*)(row + seg * 32 + q * 8) = hv;
        *(f16x8*)(row + 128 + seg * 32 + q * 8) = lv;
    }
}

// ---------------- K3: x -> planes + x_sq + packed init (fused) -------------
__global__ __launch_bounds__(256) void xprep_kernel(const float* __restrict__ x,
                                                    _Float16* __restrict__ xhl,
                                                    float* __restrict__ xsq,
                                                    unsigned long long* __restrict__ packed) {
    __shared__ float xt[128 * 65];            // [c][n], pad 65
    const int t = threadIdx.x;
    const int n0 = blockIdx.x * 64;
    const int b = n0 >> 10, hw0 = n0 & 1023;
    const float* xg = x + (size_t)b * (DIM * HW) + hw0;
    #pragma unroll
    for (int i = 0; i < 16; ++i) {
        int idx = i * 256 + t;                // 4096 float2
        int c = idx >> 5, n2 = (idx & 31) << 1;
        float2 v = *(const float2*)(xg + c * HW + n2);
        xt[c * 65 + n2] = v.x;
        xt[c * 65 + n2 + 1] = v.y;
    }
    __syncthreads();
    if (t < 64) {
        packed[n0 + t] = ~0ull;
        float s = 0.f;                        // strict c order, fp32 (== ref path)
        #pragma unroll
        for (int c = 0; c < DIM; ++c) {
            float v = xt[c * 65 + t];
            s = fmaf(v, v, s);
        }
        xsq[n0 + t] = s;
    }
    const int n = t >> 2, seg = t & 3;
    _Float16* row = xhl + (size_t)(n0 + n) * 256;
    #pragma unroll
    for (int q = 0; q < 4; ++q) {
        f16x8 hv, lv;
        #pragma unroll
        for (int j = 0; j < 8; ++j) {
            float v = 32.0f * xt[(seg * 32 + q * 8 + j) * 65 + n];
            _Float16 h = (_Float16)v;
            _Float16 l = (_Float16)(v - (float)h);
            hv[j] = h; lv[j] = l;
        }
        *(f16x8*)(row + seg * 32 + q * 8) = hv;
        *(f16x8*)(row + 128 + seg * 32 + q * 8) = lv;
    }
}

// ---------------- K4 (R14): R12 + nontemporal enc stores (f32x4 fix) -------
// 1D grid 1024 blocks x 512 thr (8 waves 2n x 4k). Block: 128n x 1024k via
// 32 (ks,c0) steps. LDS dbuf 64KB, global_load_lds w=16, T21 both-sides
// XOR swizzle, per-ni X frags, nksup=4, XCD-grouped ids (R12, verified).
// Theory: 512 MB of enc zero stores cycling through the 4 MB per-XCD L2
// evicts whl + shared X tiles, inflating staging loads from ~200cy L2-hit
// to 600-900cy L3/HBM; at 2-deep block residency that latency lands on the
// critical path each barrier. Fix: enc fill stores NONTEMPORAL
// (global_store_dwordx4 nt) -> no L2 allocation. Pure cache hint;
// numerics/addresses unchanged. (R13 compile fix: builtin requires a true
// clang vector type -> use f32x4 ext_vector, not HIP float4 struct.)
__global__ __launch_bounds__(512) void dist_argmin(
    const _Float16* __restrict__ xhl, const _Float16* __restrict__ whl,
    const float* __restrict__ wsq, const float* __restrict__ xsq,
    unsigned long long* __restrict__ packed, float* __restrict__ enc)
{
    __shared__ __align__(16) char xlds[2][16384];   // [128 rows][128 B] linear
    __shared__ __align__(16) char wlds[2][16384];
    __shared__ float xsq_s[128];
    __shared__ unsigned long long red[128];

    const int tid  = threadIdx.x;
    const int lane = tid & 63, wave = tid >> 6;     // wave 0..7
    const int lq   = lane & 15, quad = lane >> 4;
    const int wn0  = (wave >> 2) * 64;              // 0 | 64
    const int wk0q = (wave & 3) * 32;               // 0,32,64,96 in k-chunk

    // ---- XCD-grouped decode: t = n-tile (0..255), y = ksup (0..3) --------
    const int id  = blockIdx.x;
    const int xcd = id & 7, q = id >> 3;
    const int y   = q & 3;
    const int t   = (q >> 2) * 8 + xcd;
    const int n0    = t * 128;
    const int kbase = y * 1024;                     // k-row base

    // ---- staging constants: dest = buf + wave*2048 + i*1024 + lane*16 ->
    // row = wave*16 + i*8 + (lane>>3), pc = (lane&7)*16; wave*16 = 0 mod 8
    // so row&7 = lane>>3 (same verified swizzle math). ---------------------
    const int r0 = wave * 16 + (lane >> 3);               // row at i=0
    const int lc = (((lane & 7) ^ (lane >> 3)) << 4);     // logical byte col
    const int lcAdj = lc + ((lc >> 6) * 192);             // l-plane: +192
    const char* xB = (const char*)xhl;
    const char* wB = (const char*)whl;
    const size_t xrow0 = (size_t)(n0 + r0) * 512;

    // ---- fragment read offsets (logical [h32|l32] row, XOR swizzle) ------
    const int swz  = (lq & 7) << 4;
    const int hoff = (quad << 4) ^ swz;
    const int loff = (64 | (quad << 4)) ^ swz;

    float* ebase = enc + (size_t)n0 * K_CODES + kbase;
    if (tid < 128) {
        float2 z2; z2.x = 0.f; z2.y = 0.f;
        *(float2*)(ebase + (size_t)tid * K_CODES) = z2;   // head cols 0..1
        xsq_s[tid] = xsq[n0 + tid];
        red[tid] = ~0ull;
    }

#define GLOAD16(gp, lp) __builtin_amdgcn_global_load_lds(                      \
        (const __attribute__((address_space(1))) void*)(gp),                   \
        (__attribute__((address_space(3))) void*)(lp), 16, 0, 0)

    // ---- prologue: stage step 0 (ks=0, c0=0) into buffer 0 ---------------
    {
        const size_t wrow0 = (size_t)(kbase + r0) * 512;
        #pragma unroll
        for (int i = 0; i < 2; ++i) {
            GLOAD16(xB + xrow0 + (size_t)i * 4096 + lcAdj,
                    xlds[0] + wave * 2048 + i * 1024);
            GLOAD16(wB + wrow0 + (size_t)i * 4096 + lcAdj,
                    wlds[0] + wave * 2048 + i * 1024);
        }
    }

    f32x4 acc[4][2];
    float wk[2];

    for (int s = 0; s < 32; ++s) {
        const int p  = s & 1;
        const int ks = s >> 2, c0 = s & 3;
        const int k0 = kbase + ks * 128;
        if (c0 == 0) {
            wk[0] = wsq[k0 + wk0q + lq];
            wk[1] = wsq[k0 + wk0q + 16 + lq];
            #pragma unroll
            for (int i = 0; i < 4; ++i)
                #pragma unroll
                for (int j = 0; j < 2; ++j)
                    acc[i][j] = (f32x4){0.f, 0.f, 0.f, 0.f};
        }
        // barrier (with compiler vmcnt/lgkmcnt drain): step-s staging landed;
        // all waves' step s-1 LDS reads retired -> safe to re-stage buf[p^1].
        __syncthreads();

        const char* xb = xlds[p];
        const char* wb = wlds[p];

        // W frags (small, shared across ni): 32 VGPR live
        f16x8 bh[2], bl[2];
        #pragma unroll
        for (int ki = 0; ki < 2; ++ki) {
            int wr = (wk0q + 16 * ki + lq) * 128;
            bh[ki] = *(const f16x8*)(wb + wr + hoff);
            bl[ki] = *(const f16x8*)(wb + wr + loff);
        }

        // stage step s+1 into buf[p^1] (async; completes by next barrier)
        if (s < 31) {
            const int s1 = s + 1, ks1 = s1 >> 2, c01 = s1 & 3;
            const int offX = c01 * 64 + lcAdj;
            const size_t wrow0 = (size_t)(kbase + ks1 * 128 + r0) * 512;
            char* xd = xlds[p ^ 1] + wave * 2048;
            char* wd = wlds[p ^ 1] + wave * 2048;
            #pragma unroll
            for (int i = 0; i < 2; ++i) {
                GLOAD16(xB + xrow0 + (size_t)i * 4096 + offX, xd + i * 1024);
                GLOAD16(wB + wrow0 + (size_t)i * 4096 + offX, wd + i * 1024);
            }
        }

        // enc zero-fill batch s: NONTEMPORAL stores (no L2 allocation).
        // Same verified mapping: 128 rows x 256 float4-slots, +2 shift,
        // spills zero-over-zero / idxf head (overwritten by combine).
        {
            f32x4 z4 = (f32x4){0.f, 0.f, 0.f, 0.f};
            #pragma unroll
            for (int j = 0; j < 2; ++j) {
                int idx = s * 1024 + j * 512 + tid;
                int r = idx >> 8, c4 = idx & 255;
                __builtin_nontemporal_store(
                    z4, (f32x4*)(ebase + (size_t)r * K_CODES + 2 + c4 * 4));
            }
        }

        // MFMA nest, X frags scoped per-ni (16 VGPR live instead of 64)
        #pragma unroll
        for (int ni = 0; ni < 4; ++ni) {
            int xr = (wn0 + 16 * ni + lq) * 128;
            f16x8 ah = *(const f16x8*)(xb + xr + hoff);
            f16x8 al = *(const f16x8*)(xb + xr + loff);
            #pragma unroll
            for (int ki = 0; ki < 2; ++ki) {
                acc[ni][ki] = __builtin_amdgcn_mfma_f32_16x16x32_f16(
                    ah, bh[ki], acc[ni][ki], 0, 0, 0);
                acc[ni][ki] = __builtin_amdgcn_mfma_f32_16x16x32_f16(
                    ah, bl[ki], acc[ni][ki], 0, 0, 0);
                acc[ni][ki] = __builtin_amdgcn_mfma_f32_16x16x32_f16(
                    al, bh[ki], acc[ni][ki], 0, 0, 0);
            }
        }

        if (c0 == 3) {   // per-ks epilogue: distances + argmin -> LDS red[]
            #pragma unroll
            for (int ni = 0; ni < 4; ++ni) {
                #pragma unroll
                for (int rg = 0; rg < 4; ++rg) {
                    int rowl = wn0 + ni * 16 + quad * 4 + rg;
                    float xr = xsq_s[rowl];
                    float best = 3.4e38f; int bk = 0;
                    #pragma unroll
                    for (int ki = 0; ki < 2; ++ki) {
                        int kl = wk0q + ki * 16 + lq;
                        float tt = xr - acc[ni][ki][rg] * 6.103515625e-05f; // 2^-14
                        tt += wk[ki];
                        tt += 1e-8f;
                        if (tt < best) { best = tt; bk = k0 + kl; }
                    }
                    unsigned u = __float_as_uint(best);
                    u = (u & 0x80000000u) ? ~u : (u | 0x80000000u);
                    unsigned long long pck =
                        ((unsigned long long)u << 32) | (unsigned)bk;
                    #pragma unroll
                    for (int m = 1; m < 16; m <<= 1) {
                        unsigned long long o = __shfl_xor(pck, m, 64);
                        if (o < pck) pck = o;
                    }
                    if (lq == 0) atomicMin(&red[rowl], pck);
                }
            }
        }
    }
#undef GLOAD16

    __syncthreads();
    if (tid < 128) atomicMin(&packed[n0 + tid], red[tid]);
}

// ---------------- K5: combine -> indices, one-hot 1.0, counts ---------------
__global__ __launch_bounds__(256) void combine(
    const unsigned long long* __restrict__ packed,
    float* __restrict__ idxf, float* __restrict__ enc,
    float* __restrict__ counts)
{
    int n = blockIdx.x * 256 + threadIdx.x;
    unsigned k = (unsigned)(packed[n] & 0xFFFFFFFFu);
    idxf[n] = (float)k;
    enc[(size_t)n * K_CODES + k] = 1.0f;
    atomicAdd(&counts[k], 1.0f);
}

// ---------------- K6: gather -> quantized_st (NCHW) + per-block loss partial
__global__ __launch_bounds__(256) void quantize_loss(
    const float* __restrict__ x, const float* __restrict__ w,
    const float* __restrict__ idxf, float* __restrict__ outq,
    float* __restrict__ part)
{
    const int base4 = (blockIdx.x * 256 + threadIdx.x) * 4;
    float s = 0.f;
    #pragma unroll
    for (int i = 0; i < 4; ++i) {
        int e  = base4 + i * 1048576;      // NCHW element index (x4 aligned)
        int hw = e & 1023;
        int c  = (e >> 10) & 127;
        int b  = e >> 17;
        int n  = (b << 10) | hw;           // multiple of 4
        float4 xv = *(const float4*)(x + e);
        float4 kf = *(const float4*)(idxf + n);
        float q0 = w[(int)kf.x * DIM + c];
        float q1 = w[(int)kf.y * DIM + c];
        float q2 = w[(int)kf.z * DIM + c];
        float q3 = w[(int)kf.w * DIM + c];
        float4 df; df.x = q0 - xv.x; df.y = q1 - xv.y;
                   df.z = q2 - xv.z; df.w = q3 - xv.w;
        f32x4 o;  o[0] = xv.x + df.x; o[1] = xv.y + df.y;
                  o[2] = xv.z + df.z; o[3] = xv.w + df.w;
        __builtin_nontemporal_store(o, (f32x4*)(outq + e));   // streaming out
        s = fmaf(df.x, df.x, s);
        s = fmaf(df.y, df.y, s);
        s = fmaf(df.z, df.z, s);
        s = fmaf(df.w, df.w, s);
    }
    #pragma unroll
    for (int o = 32; o > 0; o >>= 1) s += __shfl_down(s, o, 64);
    __shared__ float ls[4];
    if ((threadIdx.x & 63) == 0) ls[threadIdx.x >> 6] = s;
    __syncthreads();
    if (threadIdx.x == 0) part[blockIdx.x] = ls[0] + ls[1] + ls[2] + ls[3];
}

// ---------------- K7: loss (from partials) + perplexity ---------------------
__global__ __launch_bounds__(256) void finalize(
    const float* __restrict__ counts, const float* __restrict__ part,
    float* __restrict__ out)
{
    __shared__ float sh[512];
    float h = 0.f;
    for (int k = threadIdx.x; k < K_CODES; k += 256) {
        float p = counts[k] * (1.0f / N_FLAT);
        h += p * logf(p + 1e-10f);
    }
    float s = 0.f;
    for (int i = threadIdx.x; i < 1024; i += 256) s += part[i];
    sh[threadIdx.x] = h;
    sh[256 + threadIdx.x] = s;
    __syncthreads();
    #pragma unroll
    for (int st = 128; st > 0; st >>= 1) {
        if (threadIdx.x < st) {
            sh[threadIdx.x] += sh[threadIdx.x + st];
            sh[256 + threadIdx.x] += sh[256 + threadIdx.x + st];
        }
        __syncthreads();
    }
    if (threadIdx.x == 0) {
        float perp = expf(-sh[0]);
        float loss = 1.25f * (sh[256] / 4194304.0f);
        if (isnan(loss) || isinf(loss)) loss = 0.1f;
        out[OFF_LOSS] = loss;
        out[OFF_PERP] = perp;
    }
}

extern "C" void kernel_launch(void* const* d_in, const int* in_sizes, int n_in,
                              void* d_out, int out_size, void* d_ws, size_t ws_size,
                              hipStream_t stream) {
    const float* x = (const float*)d_in[0];   // [32,128,32,32] fp32 NCHW
    const float* w = (const float*)d_in[1];   // [4096,128] fp32
    float* out = (float*)d_out;
    char* ws = (char*)d_ws;

    unsigned long long* packed = (unsigned long long*)(ws + WS_PACKED);
    float* counts = (float*)(ws + WS_COUNTS);
    float* wsq    = (float*)(ws + WS_WSQ);
    float* xsq    = (float*)(ws + WS_XSQ);
    float* part   = (float*)(ws + WS_PART);
    _Float16* xhl = (_Float16*)(ws + WS_XHL);
    _Float16* whl = (_Float16*)(ws + WS_WHL);

    wsq_kernel<<<K_CODES / 4, 256, 0, stream>>>(w, wsq, counts);
    wplanes_kernel<<<K_CODES * 4 / 256, 256, 0, stream>>>(w, whl);
    xprep_kernel<<<N_FLAT / 64, 256, 0, stream>>>(x, xhl, xsq, packed);

    dist_argmin<<<1024, 512, 0, stream>>>(xhl, whl, wsq, xsq, packed,
                                          out + OFF_ENC);

    combine<<<N_FLAT / 256, 256, 0, stream>>>(packed, out + OFF_IDX,
                                              out + OFF_ENC, counts);

    quantize_loss<<<1024, 256, 0, stream>>>(x, w, out + OFF_IDX,
                                            out + OFF_Q, part);

    finalize<<<1, 256, 0, stream>>>(counts, part, out);
}

// Round 15
// 708.862 us; speedup vs baseline: 1.0865x; 1.0051x over previous
//
#include <hip/hip_runtime.h>
#include <stdint.h>
#include <math.h>

#define K_CODES 4096
#define DIM 128
#define N_FLAT 32768      // 32 * 32 * 32
#define HW 1024           // 32*32 spatial per batch

// output offsets (floats): quantized_st, loss, perplexity, encodings, indices
#define OFF_Q    0
#define OFF_LOSS 4194304
#define OFF_PERP 4194305
#define OFF_ENC  4194306
#define OFF_IDX  138412034

// workspace offsets (bytes)
#define WS_PACKED 0                        // 32768 * 8
#define WS_COUNTS 262144                   // 4096 * 4
#define WS_WSQ    278528                   // 4096 * 4
#define WS_XSQ    294912                   // 32768 * 4
#define WS_PART   425984                   // 1024 * 4
#define WS_XHL    430080                   // 32768 rows * 256 f16 = 16 MB
#define WS_WHL    (WS_XHL + 16777216)      // 4096 rows * 256 f16 = 2 MB

typedef _Float16 f16x8 __attribute__((ext_vector_type(8)));
typedef float    f32x4 __attribute__((ext_vector_type(4)));

// f16 plane rows: [row][0:128]=h, [row][128:256]=l (512 B). Exact pow2
// scales x*32, w*1024 -> acc = 2^15*dot, unscale by 2^-14 is exact.

// ---------------- K1: w_sq + counts zero. grid 1024 x 256 (4 waves = 4 k) --
// NOTE: summation order (per-lane a*a+b*b then 64-lane shuffle tree) is
// part of the verified numerics -- do not restructure.
__global__ __launch_bounds__(256) void wsq_kernel(const float* __restrict__ w,
                                                  float* __restrict__ wsq,
                                                  float* __restrict__ counts) {
    int wave = threadIdx.x >> 6, lane = threadIdx.x & 63;
    int k = blockIdx.x * 4 + wave;
    float a = w[k * DIM + lane];
    float b = w[k * DIM + lane + 64];
    float s = a * a + b * b;
    #pragma unroll
    for (int o = 32; o > 0; o >>= 1) s += __shfl_down(s, o, 64);
    if (lane == 0) { wsq[k] = s; counts[k] = 0.f; }
}

// ---------------- K2: w -> f16 h/l planes ----------------------------------
__global__ __launch_bounds__(256) void wplanes_kernel(const float* __restrict__ w,
                                                      _Float16* __restrict__ whl) {
    int T = blockIdx.x * 256 + threadIdx.x;
    int k = T >> 2, seg = T & 3;
    const float* wp = w + (size_t)k * DIM + seg * 32;
    _Float16* row = whl + (size_t)k * 256;
    #pragma unroll
    for (int q = 0; q < 4; ++q) {
        float4 a = *(const float4*)(wp + q * 8);
        float4 b = *(const float4*)(wp + q * 8 + 4);
        float vv[8] = {a.x, a.y, a.z, a.w, b.x, b.y, b.z, b.w};
        f16x8 hv, lv;
        #pragma unroll
        for (int j = 0; j < 8; ++j) {
            float v = 1024.0f * vv[j];
            _Float16 h = (_Float16)v;
            _Float16 l = (_Float16)(v - (float)h);
            hv[j] = h; lv[j] = l;
        }
        *(f16x8*)(row + seg * 32 + q * 8) = hv;
        *(f16x8*)(row + 128 + seg * 32 + q * 8) = lv;
    }
}

// ---------------- K3: x -> planes + x_sq + packed init (fused) -------------
__global__ __launch_bounds__(256) void xprep_kernel(const float* __restrict__ x,
                                                    _Float16* __restrict__ xhl,
                                                    float* __restrict__ xsq,
                                                    unsigned long long* __restrict__ packed) {
    __shared__ float xt[128 * 65];            // [c][n], pad 65
    const int t = threadIdx.x;
    const int n0 = blockIdx.x * 64;
    const int b = n0 >> 10, hw0 = n0 & 1023;
    const float* xg = x + (size_t)b * (DIM * HW) + hw0;
    #pragma unroll
    for (int i = 0; i < 16; ++i) {
        int idx = i * 256 + t;                // 4096 float2
        int c = idx >> 5, n2 = (idx & 31) << 1;
        float2 v = *(const float2*)(xg + c * HW + n2);
        xt[c * 65 + n2] = v.x;
        xt[c * 65 + n2 + 1] = v.y;
    }
    __syncthreads();
    if (t < 64) {
        packed[n0 + t] = ~0ull;
        float s = 0.f;                        // strict c order, fp32 (== ref path)
        #pragma unroll
        for (int c = 0; c < DIM; ++c) {
            float v = xt[c * 65 + t];
            s = fmaf(v, v, s);
        }
        xsq[n0 + t] = s;
    }
    const int n = t >> 2, seg = t & 3;
    _Float16* row = xhl + (size_t)(n0 + n) * 256;
    #pragma unroll
    for (int q = 0; q < 4; ++q) {
        f16x8 hv, lv;
        #pragma unroll
        for (int j = 0; j < 8; ++j) {
            float v = 32.0f * xt[(seg * 32 + q * 8 + j) * 65 + n];
            _Float16 h = (_Float16)v;
            _Float16 l = (_Float16)(v - (float)h);
            hv[j] = h; lv[j] = l;
        }
        *(f16x8*)(row + seg * 32 + q * 8) = hv;
        *(f16x8*)(row + 128 + seg * 32 + q * 8) = lv;
    }
}

// ---------------- K4 (R15 == R14, verified 712us best): --------------------
// 1D grid 1024 blocks x 512 thr (8 waves 2n x 4k). Block: 128n x 1024k via
// 32 (ks,c0) steps. LDS dbuf 64KB, global_load_lds w=16, T21 both-sides
// XOR swizzle, per-ni X frags, nksup=4, XCD-grouped ids, NONTEMPORAL enc
// zero-fill (confirmed +46us: nt keeps whl/X-tiles L2-resident).
__global__ __launch_bounds__(512) void dist_argmin(
    const _Float16* __restrict__ xhl, const _Float16* __restrict__ whl,
    const float* __restrict__ wsq, const float* __restrict__ xsq,
    unsigned long long* __restrict__ packed, float* __restrict__ enc)
{
    __shared__ __align__(16) char xlds[2][16384];   // [128 rows][128 B] linear
    __shared__ __align__(16) char wlds[2][16384];
    __shared__ float xsq_s[128];
    __shared__ unsigned long long red[128];

    const int tid  = threadIdx.x;
    const int lane = tid & 63, wave = tid >> 6;     // wave 0..7
    const int lq   = lane & 15, quad = lane >> 4;
    const int wn0  = (wave >> 2) * 64;              // 0 | 64
    const int wk0q = (wave & 3) * 32;               // 0,32,64,96 in k-chunk

    // ---- XCD-grouped decode: t = n-tile (0..255), y = ksup (0..3) --------
    const int id  = blockIdx.x;
    const int xcd = id & 7, q = id >> 3;
    const int y   = q & 3;
    const int t   = (q >> 2) * 8 + xcd;
    const int n0    = t * 128;
    const int kbase = y * 1024;                     // k-row base

    // ---- staging constants: dest = buf + wave*2048 + i*1024 + lane*16 ->
    // row = wave*16 + i*8 + (lane>>3), pc = (lane&7)*16; wave*16 = 0 mod 8
    // so row&7 = lane>>3 (same verified swizzle math). ---------------------
    const int r0 = wave * 16 + (lane >> 3);               // row at i=0
    const int lc = (((lane & 7) ^ (lane >> 3)) << 4);     // logical byte col
    const int lcAdj = lc + ((lc >> 6) * 192);             // l-plane: +192
    const char* xB = (const char*)xhl;
    const char* wB = (const char*)whl;
    const size_t xrow0 = (size_t)(n0 + r0) * 512;

    // ---- fragment read offsets (logical [h32|l32] row, XOR swizzle) ------
    const int swz  = (lq & 7) << 4;
    const int hoff = (quad << 4) ^ swz;
    const int loff = (64 | (quad << 4)) ^ swz;

    float* ebase = enc + (size_t)n0 * K_CODES + kbase;
    if (tid < 128) {
        float2 z2; z2.x = 0.f; z2.y = 0.f;
        *(float2*)(ebase + (size_t)tid * K_CODES) = z2;   // head cols 0..1
        xsq_s[tid] = xsq[n0 + tid];
        red[tid] = ~0ull;
    }

#define GLOAD16(gp, lp) __builtin_amdgcn_global_load_lds(                      \
        (const __attribute__((address_space(1))) void*)(gp),                   \
        (__attribute__((address_space(3))) void*)(lp), 16, 0, 0)

    // ---- prologue: stage step 0 (ks=0, c0=0) into buffer 0 ---------------
    {
        const size_t wrow0 = (size_t)(kbase + r0) * 512;
        #pragma unroll
        for (int i = 0; i < 2; ++i) {
            GLOAD16(xB + xrow0 + (size_t)i * 4096 + lcAdj,
                    xlds[0] + wave * 2048 + i * 1024);
            GLOAD16(wB + wrow0 + (size_t)i * 4096 + lcAdj,
                    wlds[0] + wave * 2048 + i * 1024);
        }
    }

    f32x4 acc[4][2];
    float wk[2];

    for (int s = 0; s < 32; ++s) {
        const int p  = s & 1;
        const int ks = s >> 2, c0 = s & 3;
        const int k0 = kbase + ks * 128;
        if (c0 == 0) {
            wk[0] = wsq[k0 + wk0q + lq];
            wk[1] = wsq[k0 + wk0q + 16 + lq];
            #pragma unroll
            for (int i = 0; i < 4; ++i)
                #pragma unroll
                for (int j = 0; j < 2; ++j)
                    acc[i][j] = (f32x4){0.f, 0.f, 0.f, 0.f};
        }
        // barrier (with compiler vmcnt/lgkmcnt drain): step-s staging landed;
        // all waves' step s-1 LDS reads retired -> safe to re-stage buf[p^1].
        __syncthreads();

        const char* xb = xlds[p];
        const char* wb = wlds[p];

        // W frags (small, shared across ni): 32 VGPR live
        f16x8 bh[2], bl[2];
        #pragma unroll
        for (int ki = 0; ki < 2; ++ki) {
            int wr = (wk0q + 16 * ki + lq) * 128;
            bh[ki] = *(const f16x8*)(wb + wr + hoff);
            bl[ki] = *(const f16x8*)(wb + wr + loff);
        }

        // stage step s+1 into buf[p^1] (async; completes by next barrier)
        if (s < 31) {
            const int s1 = s + 1, ks1 = s1 >> 2, c01 = s1 & 3;
            const int offX = c01 * 64 + lcAdj;
            const size_t wrow0 = (size_t)(kbase + ks1 * 128 + r0) * 512;
            char* xd = xlds[p ^ 1] + wave * 2048;
            char* wd = wlds[p ^ 1] + wave * 2048;
            #pragma unroll
            for (int i = 0; i < 2; ++i) {
                GLOAD16(xB + xrow0 + (size_t)i * 4096 + offX, xd + i * 1024);
                GLOAD16(wB + wrow0 + (size_t)i * 4096 + offX, wd + i * 1024);
            }
        }

        // enc zero-fill batch s: NONTEMPORAL stores (no L2 allocation).
        // 128 rows x 256 float4-slots, +2 shift, spills zero-over-zero /
        // idxf head (overwritten by fused quantize_loss writer threads).
        {
            f32x4 z4 = (f32x4){0.f, 0.f, 0.f, 0.f};
            #pragma unroll
            for (int j = 0; j < 2; ++j) {
                int idx = s * 1024 + j * 512 + tid;
                int r = idx >> 8, c4 = idx & 255;
                __builtin_nontemporal_store(
                    z4, (f32x4*)(ebase + (size_t)r * K_CODES + 2 + c4 * 4));
            }
        }

        // MFMA nest, X frags scoped per-ni (16 VGPR live instead of 64)
        #pragma unroll
        for (int ni = 0; ni < 4; ++ni) {
            int xr = (wn0 + 16 * ni + lq) * 128;
            f16x8 ah = *(const f16x8*)(xb + xr + hoff);
            f16x8 al = *(const f16x8*)(xb + xr + loff);
            #pragma unroll
            for (int ki = 0; ki < 2; ++ki) {
                acc[ni][ki] = __builtin_amdgcn_mfma_f32_16x16x32_f16(
                    ah, bh[ki], acc[ni][ki], 0, 0, 0);
                acc[ni][ki] = __builtin_amdgcn_mfma_f32_16x16x32_f16(
                    ah, bl[ki], acc[ni][ki], 0, 0, 0);
                acc[ni][ki] = __builtin_amdgcn_mfma_f32_16x16x32_f16(
                    al, bh[ki], acc[ni][ki], 0, 0, 0);
            }
        }

        if (c0 == 3) {   // per-ks epilogue: distances + argmin -> LDS red[]
            #pragma unroll
            for (int ni = 0; ni < 4; ++ni) {
                #pragma unroll
                for (int rg = 0; rg < 4; ++rg) {
                    int rowl = wn0 + ni * 16 + quad * 4 + rg;
                    float xr = xsq_s[rowl];
                    float best = 3.4e38f; int bk = 0;
                    #pragma unroll
                    for (int ki = 0; ki < 2; ++ki) {
                        int kl = wk0q + ki * 16 + lq;
                        float tt = xr - acc[ni][ki][rg] * 6.103515625e-05f; // 2^-14
                        tt += wk[ki];
                        tt += 1e-8f;
                        if (tt < best) { best = tt; bk = k0 + kl; }
                    }
                    unsigned u = __float_as_uint(best);
                    u = (u & 0x80000000u) ? ~u : (u | 0x80000000u);
                    unsigned long long pck =
                        ((unsigned long long)u << 32) | (unsigned)bk;
                    #pragma unroll
                    for (int m = 1; m < 16; m <<= 1) {
                        unsigned long long o = __shfl_xor(pck, m, 64);
                        if (o < pck) pck = o;
                    }
                    if (lq == 0) atomicMin(&red[rowl], pck);
                }
            }
        }
    }
#undef GLOAD16

    __syncthreads();
    if (tid < 128) atomicMin(&packed[n0 + tid], red[tid]);
}

// ---------------- K5 (R15): gather + loss partial + FUSED combine ----------
// combine kernel eliminated: all threads derive k from packed (not idxf;
// packed = 256 KB, L2-resident). Exactly ONE writer thread per 4-n group
// (condition c == hw&127; hw is a multiple of 4 so hw&127 hits the same
// {0,4,...,124} set as candidate c's; for group (b0,hw) the unique writer
// is block blk=(b0<<7)|(hw&127), thread t=hw/4 -> 8 writer threads in each
// of 256 blocks) writes idxf float4, the 4 one-hot enc entries, and 4
// counts atomics -- same stores/values as the old combine, bit-identical.
__global__ __launch_bounds__(256) void quantize_loss(
    const float* __restrict__ x, const float* __restrict__ w,
    const unsigned long long* __restrict__ packed,
    float* __restrict__ outq, float* __restrict__ idxf,
    float* __restrict__ enc, float* __restrict__ counts,
    float* __restrict__ part)
{
    const int base4 = (blockIdx.x * 256 + threadIdx.x) * 4;
    const int c  = (base4 >> 10) & 127;
    const int hw = base4 & 1023;
    const bool writer = (c == (hw & 127));
    float s = 0.f;
    #pragma unroll
    for (int i = 0; i < 4; ++i) {
        int e = base4 + i * 1048576;       // NCHW element index (x4 aligned)
        int b = e >> 17;
        int n = (b << 10) | hw;            // multiple of 4
        float4 xv = *(const float4*)(x + e);
        ulonglong2 pa = *(const ulonglong2*)(packed + n);
        ulonglong2 pb = *(const ulonglong2*)(packed + n + 2);
        unsigned k0 = (unsigned)pa.x, k1 = (unsigned)pa.y;   // low 32 = index
        unsigned k2 = (unsigned)pb.x, k3 = (unsigned)pb.y;
        float q0 = w[k0 * DIM + c];
        float q1 = w[k1 * DIM + c];
        float q2 = w[k2 * DIM + c];
        float q3 = w[k3 * DIM + c];
        float4 df; df.x = q0 - xv.x; df.y = q1 - xv.y;
                   df.z = q2 - xv.z; df.w = q3 - xv.w;
        f32x4 o;  o[0] = xv.x + df.x; o[1] = xv.y + df.y;
                  o[2] = xv.z + df.z; o[3] = xv.w + df.w;
        __builtin_nontemporal_store(o, (f32x4*)(outq + e));   // streaming out
        s = fmaf(df.x, df.x, s);
        s = fmaf(df.y, df.y, s);
        s = fmaf(df.z, df.z, s);
        s = fmaf(df.w, df.w, s);
        if (writer) {
            float4 kf; kf.x = (float)k0; kf.y = (float)k1;
                       kf.z = (float)k2; kf.w = (float)k3;
            *(float4*)(idxf + n) = kf;
            enc[(size_t)n       * K_CODES + k0] = 1.0f;
            enc[(size_t)(n + 1) * K_CODES + k1] = 1.0f;
            enc[(size_t)(n + 2) * K_CODES + k2] = 1.0f;
            enc[(size_t)(n + 3) * K_CODES + k3] = 1.0f;
            atomicAdd(&counts[k0], 1.0f);
            atomicAdd(&counts[k1], 1.0f);
            atomicAdd(&counts[k2], 1.0f);
            atomicAdd(&counts[k3], 1.0f);
        }
    }
    #pragma unroll
    for (int o = 32; o > 0; o >>= 1) s += __shfl_down(s, o, 64);
    __shared__ float ls[4];
    if ((threadIdx.x & 63) == 0) ls[threadIdx.x >> 6] = s;
    __syncthreads();
    if (threadIdx.x == 0) part[blockIdx.x] = ls[0] + ls[1] + ls[2] + ls[3];
}

// ---------------- K7: loss (from partials) + perplexity ---------------------
__global__ __launch_bounds__(256) void finalize(
    const float* __restrict__ counts, const float* __restrict__ part,
    float* __restrict__ out)
{
    __shared__ float sh[512];
    float h = 0.f;
    for (int k = threadIdx.x; k < K_CODES; k += 256) {
        float p = counts[k] * (1.0f / N_FLAT);
        h += p * logf(p + 1e-10f);
    }
    float s = 0.f;
    for (int i = threadIdx.x; i < 1024; i += 256) s += part[i];
    sh[threadIdx.x] = h;
    sh[256 + threadIdx.x] = s;
    __syncthreads();
    #pragma unroll
    for (int st = 128; st > 0; st >>= 1) {
        if (threadIdx.x < st) {
            sh[threadIdx.x] += sh[threadIdx.x + st];
            sh[256 + threadIdx.x] += sh[256 + threadIdx.x + st];
        }
        __syncthreads();
    }
    if (threadIdx.x == 0) {
        float perp = expf(-sh[0]);
        float loss = 1.25f * (sh[256] / 4194304.0f);
        if (isnan(loss) || isinf(loss)) loss = 0.1f;
        out[OFF_LOSS] = loss;
        out[OFF_PERP] = perp;
    }
}

extern "C" void kernel_launch(void* const* d_in, const int* in_sizes, int n_in,
                              void* d_out, int out_size, void* d_ws, size_t ws_size,
                              hipStream_t stream) {
    const float* x = (const float*)d_in[0];   // [32,128,32,32] fp32 NCHW
    const float* w = (const float*)d_in[1];   // [4096,128] fp32
    float* out = (float*)d_out;
    char* ws = (char*)d_ws;

    unsigned long long* packed = (unsigned long long*)(ws + WS_PACKED);
    float* counts = (float*)(ws + WS_COUNTS);
    float* wsq    = (float*)(ws + WS_WSQ);
    float* xsq    = (float*)(ws + WS_XSQ);
    float* part   = (float*)(ws + WS_PART);
    _Float16* xhl = (_Float16*)(ws + WS_XHL);
    _Float16* whl = (_Float16*)(ws + WS_WHL);

    wsq_kernel<<<K_CODES / 4, 256, 0, stream>>>(w, wsq, counts);
    wplanes_kernel<<<K_CODES * 4 / 256, 256, 0, stream>>>(w, whl);
    xprep_kernel<<<N_FLAT / 64, 256, 0, stream>>>(x, xhl, xsq, packed);

    dist_argmin<<<1024, 512, 0, stream>>>(xhl, whl, wsq, xsq, packed,
                                          out + OFF_ENC);

    quantize_loss<<<1024, 256, 0, stream>>>(x, w, packed, out + OFF_Q,
                                            out + OFF_IDX, out + OFF_ENC,
                                            counts, part);

    finalize<<<1, 256, 0, stream>>>(counts, part, out);
}